// Round 4
// baseline (887.954 us; speedup 1.0000x reference)
//
#include <hip/hip_runtime.h>
#include <hip/hip_bf16.h>
#include <cstdint>
#include <cstddef>

#define B_ 128
#define S_ 256
#define TOK (B_*S_)   // 32768

__device__ __forceinline__ float sigf(float x) {
    return __builtin_amdgcn_rcpf(1.0f + __expf(-x));
}
__device__ __forceinline__ float tanhfast(float x) {
    return 1.0f - 2.0f * __builtin_amdgcn_rcpf(1.0f + __expf(2.0f * x));
}
__device__ __forceinline__ float bf2f(unsigned short v) {
    union { unsigned u; float f; } c; c.u = ((unsigned)v) << 16; return c.f;
}
// Force a value to live in VGPRs (opaque to remat/reload heuristics).
__device__ __forceinline__ void pin4(float4& v) {
    asm volatile("" : "+v"(v.x), "+v"(v.y), "+v"(v.z), "+v"(v.w));
}

// ---- K1: char input-gate table: gin[dir][c][row] = b[row] + Wih[row,:]·emb[c,:]
__global__ void k_gin(const float* __restrict__ ce,
                      const float* __restrict__ wih_f, const float* __restrict__ b_f,
                      const float* __restrict__ wih_b, const float* __restrict__ b_b,
                      float* __restrict__ gin) {
    int tid = blockIdx.x * blockDim.x + threadIdx.x;
    if (tid >= 200) return;
    int dir = tid / 100, row = tid % 100;
    const float* wih = dir ? wih_b : wih_f;
    float bias = dir ? b_b[row] : b_f[row];
    for (int c = 0; c < 100; ++c) {
        float s = bias;
#pragma unroll
        for (int k = 0; k < 25; ++k) s += wih[row*25 + k] * ce[c*25 + k];
        gin[(dir*100 + c)*100 + row] = s;
    }
}

// ---- K1b: combined word-input weight [800][152] (k-padded) + bias [800]
__global__ void k_wcomb(const float* __restrict__ wih_f, const float* __restrict__ bf,
                        const float* __restrict__ wih_b, const float* __restrict__ bb,
                        float* __restrict__ Wc, float* __restrict__ bc) {
    int idx = blockIdx.x * blockDim.x + threadIdx.x;
    if (idx < 800*152) {
        int n = idx / 152, k = idx - n*152;
        int dir = n >= 400 ? 1 : 0, r = n - dir*400;
        const float* w = dir ? wih_b : wih_f;
        Wc[idx] = (k < 150) ? w[r*150 + k] : 0.0f;
    }
    if (idx < 800) {
        int dir = idx >= 400 ? 1 : 0, r = idx - dir*400;
        bc[idx] = dir ? bb[r] : bf[r];
    }
}

// ---- K2: char BiLSTM. 8 groups of 32 lanes per block; h exchanged via LDS broadcast.
__global__ __launch_bounds__(256) void k_char(
        const float* __restrict__ gin,
        const float* __restrict__ whh_f, const float* __restrict__ whh_b,
        const int* __restrict__ char_ids, const int* __restrict__ word_num,
        float* __restrict__ wfbuf) {
    __shared__ __align__(16) float hsm[8][28];   // per-group h, padded 25->28
    int tid  = threadIdx.x;
    int grp  = tid >> 5, lane = tid & 31;
    int g    = blockIdx.x * 8 + grp;        // (word,dir) id: 0..65535
    int word = g >> 1, dir = g & 1;
    int b    = word >> 8, s = word & 255;
    const float* whh = dir ? whh_b : whh_f;
    int k = (lane < 25) ? lane : 0;
    // weights: w[gate][j4] over prev-h index j (28-padded, zeros past 25); PINNED
    float4 w[4][7];
#pragma unroll
    for (int gi = 0; gi < 4; ++gi)
#pragma unroll
        for (int j4 = 0; j4 < 7; ++j4) {
            const float* row = &whh[(gi*25 + k)*25];
            float4 v;
            v.x = (j4*4+0 < 25) ? row[j4*4+0] : 0.f;
            v.y = (j4*4+1 < 25) ? row[j4*4+1] : 0.f;
            v.z = (j4*4+2 < 25) ? row[j4*4+2] : 0.f;
            v.w = (j4*4+3 < 25) ? row[j4*4+3] : 0.f;
            pin4(v);
            w[gi][j4] = v;
        }
    if (lane < 28) hsm[grp][lane] = 0.f;    // h0 = 0, pad = 0 (kills LDS poison)
    int chs[16];
#pragma unroll
    for (int t = 0; t < 16; ++t) chs[t] = char_ids[word*16 + t];
    float h = 0.f, c = 0.f;
#pragma unroll
    for (int tt = 0; tt < 16; ++tt) {
        int t  = dir ? (15 - tt) : tt;
        const float* gv = gin + (dir*100 + chs[t])*100;
        float ai = gv[k], af = gv[25 + k], ag = gv[50 + k], ao = gv[75 + k];
        const float4* hp = (const float4*)hsm[grp];
#pragma unroll
        for (int j4 = 0; j4 < 7; ++j4) {
            float4 h4 = hp[j4];   // same-addr broadcast within group (free)
            ai += w[0][j4].x*h4.x + w[0][j4].y*h4.y + w[0][j4].z*h4.z + w[0][j4].w*h4.w;
            af += w[1][j4].x*h4.x + w[1][j4].y*h4.y + w[1][j4].z*h4.z + w[1][j4].w*h4.w;
            ag += w[2][j4].x*h4.x + w[2][j4].y*h4.y + w[2][j4].z*h4.z + w[2][j4].w*h4.w;
            ao += w[3][j4].x*h4.x + w[3][j4].y*h4.y + w[3][j4].z*h4.z + w[3][j4].w*h4.w;
        }
        c = sigf(af)*c + sigf(ai)*tanhfast(ag);
        h = sigf(ao)*tanhfast(c);
        if (lane < 25) hsm[grp][k] = h;     // wave-synchronous: in-order DS pipe
    }
    if (lane < 25) {
        float m = (s < word_num[b]) ? 1.f : 0.f;
        wfbuf[(size_t)word*152 + 100 + dir*25 + lane] = h * m;  // [hf | hb], masked
    }
}

// ---- K3a: gather word embeddings into wfbuf[:,0:100]; zero k-pad 150..151
__global__ void k_gather(const float* __restrict__ we, const int* __restrict__ wids,
                         float* __restrict__ wfbuf) {
    int idx = blockIdx.x * blockDim.x + threadIdx.x;
    if (idx >= TOK*152) return;
    int t = idx / 152, e = idx - t*152;
    if (e < 100)        wfbuf[idx] = we[(size_t)wids[t]*100 + e];
    else if (e >= 150)  wfbuf[idx] = 0.f;
}

// ---- K3b: word input gates GEMM  [32768,152] @ [152,800] -> bf16 gates [t][r]
__global__ __launch_bounds__(256) void k_gemm_in(
        const float* __restrict__ A, const float* __restrict__ Wc,
        const float* __restrict__ bc, __hip_bfloat16* __restrict__ gates) {
    __shared__ float As[8][64];
    __shared__ float Bs[8][64];
    int tid = threadIdx.x;
    int tileM = blockIdx.x & 511;
    int tileN = blockIdx.x >> 9;        // 0..12
    int m0 = tileM*64, n0 = tileN*64;
    int ty = tid >> 4, tx = tid & 15;
    int a_m = tid >> 2, a_k = (tid & 3)*2;
    float acc[4][4] = {};
    for (int k0 = 0; k0 < 152; k0 += 8) {
        float2 av = *(const float2*)&A[(size_t)(m0 + a_m)*152 + k0 + a_k];
        float2 bv = make_float2(0.f, 0.f);
        if (n0 + a_m < 800)
            bv = *(const float2*)&Wc[(size_t)(n0 + a_m)*152 + k0 + a_k];
        __syncthreads();
        As[a_k][a_m] = av.x; As[a_k+1][a_m] = av.y;
        Bs[a_k][a_m] = bv.x; Bs[a_k+1][a_m] = bv.y;
        __syncthreads();
#pragma unroll
        for (int kk = 0; kk < 8; ++kk) {
            float4 a4 = *(const float4*)&As[kk][ty*4];
            float4 b4 = *(const float4*)&Bs[kk][tx*4];
            float am[4] = {a4.x, a4.y, a4.z, a4.w};
            float bn[4] = {b4.x, b4.y, b4.z, b4.w};
#pragma unroll
            for (int p = 0; p < 4; ++p)
#pragma unroll
                for (int q = 0; q < 4; ++q) acc[p][q] += am[p]*bn[q];
        }
    }
#pragma unroll
    for (int p = 0; p < 4; ++p) {
        int m = m0 + ty*4 + p;
#pragma unroll
        for (int q = 0; q < 4; ++q) {
            int n = n0 + tx*4 + q;
            if (n < 800) {
                int dir = n >= 400 ? 1 : 0, r = n - dir*400;
                gates[((size_t)dir*TOK + m)*400 + r] = __float2bfloat16(acc[p][q] + bc[n]);
            }
        }
    }
}

// ---- K4: word BiLSTM. 256 blocks=(b,dir); thread owns all 4 gate rows of unit u,
//          k-split across wave halves; 1 barrier/step; pinned weights; gate prefetch.
__global__ __launch_bounds__(256, 1) void k_word(
        const __hip_bfloat16* __restrict__ gates,
        const float* __restrict__ whh_f, const float* __restrict__ whh_b,
        __hip_bfloat16* __restrict__ wh) {
    int b = blockIdx.x >> 1, dir = blockIdx.x & 1;
    int tid = threadIdx.x;
    int wv   = tid >> 6;            // wave 0..3
    int lane = tid & 63;
    int q    = lane >> 5;           // k-half: 0 -> even float4 chunks, 1 -> odd
    int u    = wv*32 + (lane & 31); // unit 0..127
    bool act = (u < 100);
    const float* whh = dir ? whh_b : whh_f;
    __shared__ __align__(16) float hs[2][112];   // double-buffered h, padded
    for (int i = tid; i < 224; i += 256) ((float*)hs)[i] = 0.f;
    // weights: W[gate][i] = Whh[gate*100+u][4*(2i+q) .. +3], zero beyond k=100; PINNED
    float4 W[4][13];
#pragma unroll
    for (int gi = 0; gi < 4; ++gi)
#pragma unroll
        for (int i = 0; i < 13; ++i) {
            int ch = 2*i + q;
            float4 v;
            if (act && ch < 25)
                v = *(const float4*)&whh[(size_t)(gi*100 + u)*100 + ch*4];
            else
                v = make_float4(0.f, 0.f, 0.f, 0.f);
            pin4(v);
            W[gi][i] = v;
        }
    float cst = 0.f;
    const unsigned short* gp = (const unsigned short*)gates
                             + (size_t)(dir*TOK + b*256)*400;   // [t][gate*100+u]
    __syncthreads();
    int t0 = dir ? 255 : 0;
    unsigned short G0 = 0, G1 = 0, G2 = 0, G3 = 0;
    if (act) {
        const unsigned short* p = gp + (size_t)t0*400 + u;
        G0 = p[0]; G1 = p[100]; G2 = p[200]; G3 = p[300];
    }
    for (int tt = 0; tt < 256; ++tt) {
        int t = dir ? (255 - tt) : tt;
        float gI = bf2f(G0), gF = bf2f(G1), gG = bf2f(G2), gO = bf2f(G3);
        if (tt < 255 && act) {
            int tn = dir ? (t - 1) : (t + 1);
            const unsigned short* p = gp + (size_t)tn*400 + u;
            G0 = p[0]; G1 = p[100]; G2 = p[200]; G3 = p[300];
        }
        const float4* hp = (const float4*)hs[tt & 1];
        float a0 = 0.f, a1 = 0.f, a2 = 0.f, a3 = 0.f;
#pragma unroll
        for (int i = 0; i < 13; ++i) {
            float4 h4 = hp[2*i + q];    // same-addr broadcast per half (free 2-way)
            a0 += W[0][i].x*h4.x + W[0][i].y*h4.y + W[0][i].z*h4.z + W[0][i].w*h4.w;
            a1 += W[1][i].x*h4.x + W[1][i].y*h4.y + W[1][i].z*h4.z + W[1][i].w*h4.w;
            a2 += W[2][i].x*h4.x + W[2][i].y*h4.y + W[2][i].z*h4.z + W[2][i].w*h4.w;
            a3 += W[3][i].x*h4.x + W[3][i].y*h4.y + W[3][i].z*h4.z + W[3][i].w*h4.w;
        }
        a0 += __shfl_xor(a0, 32, 64);
        a1 += __shfl_xor(a1, 32, 64);
        a2 += __shfl_xor(a2, 32, 64);
        a3 += __shfl_xor(a3, 32, 64);
        gI += a0; gF += a1; gG += a2; gO += a3;
        cst = sigf(gF)*cst + sigf(gI)*tanhfast(gG);
        float h = sigf(gO)*tanhfast(cst);
        if (act && q == 0) {
            hs[(tt + 1) & 1][u] = h;
            wh[(size_t)(b*256 + t)*200 + dir*100 + u] = __float2bfloat16(h);
        }
        __syncthreads();
    }
}

// ---- K5: feats = (tanh(wh@W1^T+b1)@W2^T+b2)*mask ; 32 tokens per block
__global__ __launch_bounds__(256) void k_feats(
        const __hip_bfloat16* __restrict__ wh,
        const float* __restrict__ W1, const float* __restrict__ b1,
        const float* __restrict__ W2, const float* __restrict__ b2,
        const int* __restrict__ word_num, float* __restrict__ feats) {
    __shared__ float As[8][32];
    __shared__ float Ws[8][100];
    __shared__ float mids[32][100];
    int tid = threadIdx.x;
    int m0  = blockIdx.x * 32;
    int a_m = tid >> 3, a_k = tid & 7;
    int tn  = tid % 25, tm = tid / 25;   // active: tid < 200
    float acc[4][4] = {};
    for (int k0 = 0; k0 < 200; k0 += 8) {
        float av = __bfloat162float(wh[(size_t)(m0 + a_m)*200 + k0 + a_k]);
        int i1 = tid + 256, i2 = tid + 512, i3 = tid + 768;
        float wv0 = W1[(tid>>3)*200 + k0 + (tid&7)];
        float wv1 = W1[(i1 >>3)*200 + k0 + (i1 &7)];
        float wv2 = W1[(i2 >>3)*200 + k0 + (i2 &7)];
        float wv3 = (i3 < 800) ? W1[(i3>>3)*200 + k0 + (i3&7)] : 0.f;
        __syncthreads();
        As[a_k][a_m] = av;
        Ws[tid&7][tid>>3] = wv0;
        Ws[i1 &7][i1 >>3] = wv1;
        Ws[i2 &7][i2 >>3] = wv2;
        if (i3 < 800) Ws[i3&7][i3>>3] = wv3;
        __syncthreads();
        if (tid < 200) {
#pragma unroll
            for (int kk = 0; kk < 8; ++kk) {
                float4 a4 = *(const float4*)&As[kk][tm*4];
                float4 w4 = *(const float4*)&Ws[kk][tn*4];
                float am[4] = {a4.x, a4.y, a4.z, a4.w};
                float wn[4] = {w4.x, w4.y, w4.z, w4.w};
#pragma unroll
                for (int p = 0; p < 4; ++p)
#pragma unroll
                    for (int q = 0; q < 4; ++q) acc[p][q] += am[p]*wn[q];
            }
        }
    }
    if (tid < 200) {
#pragma unroll
        for (int p = 0; p < 4; ++p)
#pragma unroll
            for (int q = 0; q < 4; ++q)
                mids[tm*4+p][tn*4+q] = tanhfast(acc[p][q] + b1[tn*4+q]);
    }
    __syncthreads();
    for (int idx = tid; idx < 288; idx += 256) {
        int tok = idx / 9, lab = idx - tok*9;
        int m = m0 + tok, bb = m >> 8, s = m & 255;
        float v = b2[lab];
        const float4* mp = (const float4*)mids[tok];
        const float4* wp = (const float4*)(W2 + lab*100);
#pragma unroll
        for (int k = 0; k < 25; ++k) {
            float4 mv = mp[k], wv = wp[k];
            v += mv.x*wv.x + mv.y*wv.y + mv.z*wv.z + mv.w*wv.w;
        }
        feats[(size_t)m*12 + lab] = (s < word_num[bb]) ? v : 0.f;
    }
}

// ---- K6: CRF numerator + log-forward recursion. One wave per batch row.
__global__ __launch_bounds__(64) void k_crf(
        const float* __restrict__ feats, const float* __restrict__ T,
        const int* __restrict__ word_num, const int* __restrict__ label_ids,
        float* __restrict__ perb) {
    int b = blockIdx.x, lane = threadIdx.x;
    int n = word_num[b];
    const int*   lab = label_ids + b*256;
    const float* fb  = feats + (size_t)b*256*12;
    float nm = 0.f;
    for (int t = lane; t < n; t += 64) {
        int lt = lab[t];
        int lp = (t == 0) ? 9 : lab[t-1];
        nm += fb[t*12 + lt] + T[lp*11 + lt];
    }
#pragma unroll
    for (int o = 32; o > 0; o >>= 1) nm += __shfl_down(nm, o, 64);
    nm = __shfl(nm, 0, 64);
    nm += T[lab[n-1]*11 + 10];
    int j = lane;
    float Tc[11];
#pragma unroll
    for (int i = 0; i < 11; ++i) Tc[i] = T[i*11 + (j < 11 ? j : 0)];
    float alpha = (j == 9) ? 0.f : -1000.f;
    for (int t = 0; t < n; ++t) {
        float obs = (j < 9) ? fb[t*12 + j] : -1000.f;
        float v[11], mx = -1e30f;
#pragma unroll
        for (int i = 0; i < 11; ++i) { v[i] = __shfl(alpha, i, 64) + Tc[i]; mx = fmaxf(mx, v[i]); }
        float ssum = 0.f;
#pragma unroll
        for (int i = 0; i < 11; ++i) ssum += __expf(v[i] - mx);
        alpha = obs + mx + __logf(ssum);
    }
    float vv[11], mx = -1e30f, ssum = 0.f;
#pragma unroll
    for (int i = 0; i < 11; ++i) { vv[i] = __shfl(alpha, i, 64) + Tc[i]; mx = fmaxf(mx, vv[i]); }
#pragma unroll
    for (int i = 0; i < 11; ++i) ssum += __expf(vv[i] - mx);
    float denom = __shfl(mx + __logf(ssum), 10, 64);
    if (lane == 0) perb[b] = denom - nm;
}

// ---- K7: mean over batch
__global__ void k_reduce(const float* __restrict__ perb, float* __restrict__ out) {
    int t = threadIdx.x;
    float v = perb[t];
#pragma unroll
    for (int o = 32; o > 0; o >>= 1) v += __shfl_down(v, o, 64);
    __shared__ float sm[2];
    if ((t & 63) == 0) sm[t >> 6] = v;
    __syncthreads();
    if (t == 0) out[0] = (sm[0] + sm[1]) * (1.0f/128.0f);
}

extern "C" void kernel_launch(void* const* d_in, const int* in_sizes, int n_in,
                              void* d_out, int out_size, void* d_ws, size_t ws_size,
                              hipStream_t stream) {
    const float* word_emb = (const float*)d_in[0];
    const float* char_emb = (const float*)d_in[1];
    const float* cWih_f   = (const float*)d_in[2];
    const float* cWhh_f   = (const float*)d_in[3];
    const float* cb_f     = (const float*)d_in[4];
    const float* cWih_b   = (const float*)d_in[5];
    const float* cWhh_b   = (const float*)d_in[6];
    const float* cb_b     = (const float*)d_in[7];
    const float* wWih_f   = (const float*)d_in[8];
    const float* wWhh_f   = (const float*)d_in[9];
    const float* wb_f     = (const float*)d_in[10];
    const float* wWih_b   = (const float*)d_in[11];
    const float* wWhh_b   = (const float*)d_in[12];
    const float* wb_b     = (const float*)d_in[13];
    const float* W1       = (const float*)d_in[14];
    const float* b1       = (const float*)d_in[15];
    const float* W2       = (const float*)d_in[16];
    const float* b2       = (const float*)d_in[17];
    const float* T        = (const float*)d_in[18];
    const int* word_num   = (const int*)d_in[19];
    const int* word_ids   = (const int*)d_in[20];
    const int* char_ids   = (const int*)d_in[21];
    const int* label_ids  = (const int*)d_in[22];

    char* ws = (char*)d_ws;
    float* gin            = (float*)(ws);                       //    80,000 B
    float* Wc             = (float*)(ws + 80000);               //   486,400 B
    float* bc             = (float*)(ws + 566400);              //     3,200 B
    float* wfbuf          = (float*)(ws + 569600);              // 19,922,944 B [32768][152]
    __hip_bfloat16* gates = (__hip_bfloat16*)(ws + 20492544);   // 52,428,800 B [2][32768][400]
    __hip_bfloat16* wh    = (__hip_bfloat16*)(ws + 72921344);   // 13,107,200 B [32768][200]
    float* feats          = (float*)(ws + 86028544);            //  1,572,864 B [32768][12]
    float* perb           = (float*)(ws + 87601408);            //       512 B

    k_gin   <<<4, 64, 0, stream>>>(char_emb, cWih_f, cb_f, cWih_b, cb_b, gin);
    k_wcomb <<<(800*152 + 255)/256, 256, 0, stream>>>(wWih_f, wb_f, wWih_b, wb_b, Wc, bc);
    k_gather<<<(TOK*152)/256, 256, 0, stream>>>(word_emb, word_ids, wfbuf);
    k_char  <<<8192, 256, 0, stream>>>(gin, cWhh_f, cWhh_b, char_ids, word_num, wfbuf);
    k_gemm_in<<<512*13, 256, 0, stream>>>(wfbuf, Wc, bc, gates);
    k_word  <<<256, 256, 0, stream>>>(gates, wWhh_f, wWhh_b, wh);
    k_feats <<<1024, 256, 0, stream>>>(wh, W1, b1, W2, b2, word_num, feats);
    k_crf   <<<128, 64, 0, stream>>>(feats, T, word_num, label_ids, perb);
    k_reduce<<<1, 128, 0, stream>>>(perb, (float*)d_out);
}

// Round 5
// 798.316 us; speedup vs baseline: 1.1123x; 1.1123x over previous
//
#include <hip/hip_runtime.h>
#include <hip/hip_bf16.h>
#include <cstdint>
#include <cstddef>

#define B_ 128
#define S_ 256
#define TOK (B_*S_)   // 32768

__device__ __forceinline__ float sigf(float x) {
    return __builtin_amdgcn_rcpf(1.0f + __expf(-x));
}
__device__ __forceinline__ float tanhfast(float x) {
    return 1.0f - 2.0f * __builtin_amdgcn_rcpf(1.0f + __expf(2.0f * x));
}
__device__ __forceinline__ float bf2f(unsigned short v) {
    union { unsigned u; float f; } c; c.u = ((unsigned)v) << 16; return c.f;
}

// ---- K1: char input-gate table: gin[dir][c][row] = b[row] + Wih[row,:]·emb[c,:]
__global__ void k_gin(const float* __restrict__ ce,
                      const float* __restrict__ wih_f, const float* __restrict__ b_f,
                      const float* __restrict__ wih_b, const float* __restrict__ b_b,
                      float* __restrict__ gin) {
    int tid = blockIdx.x * blockDim.x + threadIdx.x;
    if (tid >= 200) return;
    int dir = tid / 100, row = tid % 100;
    const float* wih = dir ? wih_b : wih_f;
    float bias = dir ? b_b[row] : b_f[row];
    for (int c = 0; c < 100; ++c) {
        float s = bias;
#pragma unroll
        for (int k = 0; k < 25; ++k) s += wih[row*25 + k] * ce[c*25 + k];
        gin[(dir*100 + c)*100 + row] = s;
    }
}

// ---- K1b: combined word-input weight [800][152] (k-padded) + bias [800]
__global__ void k_wcomb(const float* __restrict__ wih_f, const float* __restrict__ bf,
                        const float* __restrict__ wih_b, const float* __restrict__ bb,
                        float* __restrict__ Wc, float* __restrict__ bc) {
    int idx = blockIdx.x * blockDim.x + threadIdx.x;
    if (idx < 800*152) {
        int n = idx / 152, k = idx - n*152;
        int dir = n >= 400 ? 1 : 0, r = n - dir*400;
        const float* w = dir ? wih_b : wih_f;
        Wc[idx] = (k < 150) ? w[r*150 + k] : 0.0f;
    }
    if (idx < 800) {
        int dir = idx >= 400 ? 1 : 0, r = idx - dir*400;
        bc[idx] = dir ? bb[r] : bf[r];
    }
}

// ---- K2: char BiLSTM. 8 groups of 32 lanes per block; h exchanged via LDS broadcast.
//      waves_per_eu(2,2): allocator budget 256 VGPR -> 112 weight floats stay resident.
__global__ __launch_bounds__(256)
__attribute__((amdgpu_waves_per_eu(2, 2)))
void k_char(
        const float* __restrict__ gin,
        const float* __restrict__ whh_f, const float* __restrict__ whh_b,
        const int* __restrict__ char_ids, const int* __restrict__ word_num,
        float* __restrict__ wfbuf) {
    __shared__ __align__(16) float hsm[8][28];   // per-group h, padded 25->28
    int tid  = threadIdx.x;
    int grp  = tid >> 5, lane = tid & 31;
    int g    = blockIdx.x * 8 + grp;        // (word,dir) id: 0..65535
    int word = g >> 1, dir = g & 1;
    int b    = word >> 8, s = word & 255;
    const float* whh = dir ? whh_b : whh_f;
    int k = (lane < 25) ? lane : 0;
    // weights: w[gate][j4] over prev-h index j (28-padded, zeros past 25)
    float4 w[4][7];
#pragma unroll
    for (int gi = 0; gi < 4; ++gi)
#pragma unroll
        for (int j4 = 0; j4 < 7; ++j4) {
            const float* row = &whh[(gi*25 + k)*25];
            float4 v;
            v.x = (j4*4+0 < 25) ? row[j4*4+0] : 0.f;
            v.y = (j4*4+1 < 25) ? row[j4*4+1] : 0.f;
            v.z = (j4*4+2 < 25) ? row[j4*4+2] : 0.f;
            v.w = (j4*4+3 < 25) ? row[j4*4+3] : 0.f;
            w[gi][j4] = v;
        }
    if (lane < 28) hsm[grp][lane] = 0.f;    // h0 = 0, pad = 0 (kills LDS poison)
    int chs[16];
#pragma unroll
    for (int t = 0; t < 16; ++t) chs[t] = char_ids[word*16 + t];
    float h = 0.f, c = 0.f;
#pragma unroll
    for (int tt = 0; tt < 16; ++tt) {
        int t  = dir ? (15 - tt) : tt;
        const float* gv = gin + (dir*100 + chs[t])*100;
        float ai = gv[k], af = gv[25 + k], ag = gv[50 + k], ao = gv[75 + k];
        const float4* hp = (const float4*)hsm[grp];
#pragma unroll
        for (int j4 = 0; j4 < 7; ++j4) {
            float4 h4 = hp[j4];   // same-addr broadcast within group (free)
            ai += w[0][j4].x*h4.x + w[0][j4].y*h4.y + w[0][j4].z*h4.z + w[0][j4].w*h4.w;
            af += w[1][j4].x*h4.x + w[1][j4].y*h4.y + w[1][j4].z*h4.z + w[1][j4].w*h4.w;
            ag += w[2][j4].x*h4.x + w[2][j4].y*h4.y + w[2][j4].z*h4.z + w[2][j4].w*h4.w;
            ao += w[3][j4].x*h4.x + w[3][j4].y*h4.y + w[3][j4].z*h4.z + w[3][j4].w*h4.w;
        }
        c = sigf(af)*c + sigf(ai)*tanhfast(ag);
        h = sigf(ao)*tanhfast(c);
        if (lane < 25) hsm[grp][k] = h;     // wave-synchronous: in-order DS pipe
    }
    if (lane < 25) {
        float m = (s < word_num[b]) ? 1.f : 0.f;
        wfbuf[(size_t)word*152 + 100 + dir*25 + lane] = h * m;  // [hf | hb], masked
    }
}

// ---- K3a: gather word embeddings into wfbuf[:,0:100]; zero k-pad 150..151
__global__ void k_gather(const float* __restrict__ we, const int* __restrict__ wids,
                         float* __restrict__ wfbuf) {
    int idx = blockIdx.x * blockDim.x + threadIdx.x;
    if (idx >= TOK*152) return;
    int t = idx / 152, e = idx - t*152;
    if (e < 100)        wfbuf[idx] = we[(size_t)wids[t]*100 + e];
    else if (e >= 150)  wfbuf[idx] = 0.f;
}

// ---- K3b: word input gates GEMM  [32768,152] @ [152,800] -> bf16 gates [t][r]
__global__ __launch_bounds__(256) void k_gemm_in(
        const float* __restrict__ A, const float* __restrict__ Wc,
        const float* __restrict__ bc, __hip_bfloat16* __restrict__ gates) {
    __shared__ float As[8][64];
    __shared__ float Bs[8][64];
    int tid = threadIdx.x;
    int tileM = blockIdx.x & 511;
    int tileN = blockIdx.x >> 9;        // 0..12
    int m0 = tileM*64, n0 = tileN*64;
    int ty = tid >> 4, tx = tid & 15;
    int a_m = tid >> 2, a_k = (tid & 3)*2;
    float acc[4][4] = {};
    for (int k0 = 0; k0 < 152; k0 += 8) {
        float2 av = *(const float2*)&A[(size_t)(m0 + a_m)*152 + k0 + a_k];
        float2 bv = make_float2(0.f, 0.f);
        if (n0 + a_m < 800)
            bv = *(const float2*)&Wc[(size_t)(n0 + a_m)*152 + k0 + a_k];
        __syncthreads();
        As[a_k][a_m] = av.x; As[a_k+1][a_m] = av.y;
        Bs[a_k][a_m] = bv.x; Bs[a_k+1][a_m] = bv.y;
        __syncthreads();
#pragma unroll
        for (int kk = 0; kk < 8; ++kk) {
            float4 a4 = *(const float4*)&As[kk][ty*4];
            float4 b4 = *(const float4*)&Bs[kk][tx*4];
            float am[4] = {a4.x, a4.y, a4.z, a4.w};
            float bn[4] = {b4.x, b4.y, b4.z, b4.w};
#pragma unroll
            for (int p = 0; p < 4; ++p)
#pragma unroll
                for (int q = 0; q < 4; ++q) acc[p][q] += am[p]*bn[q];
        }
    }
#pragma unroll
    for (int p = 0; p < 4; ++p) {
        int m = m0 + ty*4 + p;
#pragma unroll
        for (int q = 0; q < 4; ++q) {
            int n = n0 + tx*4 + q;
            if (n < 800) {
                int dir = n >= 400 ? 1 : 0, r = n - dir*400;
                gates[((size_t)dir*TOK + m)*400 + r] = __float2bfloat16(acc[p][q] + bc[n]);
            }
        }
    }
}

// ---- K4: word BiLSTM. 256 blocks=(b,dir); thread owns all 4 gate rows of unit u,
//      k-split across wave halves; 1 barrier/step; gate prefetch.
//      waves_per_eu(1,1): allocator budget 512 VGPR -> 208 weight floats resident.
__global__ __launch_bounds__(256)
__attribute__((amdgpu_waves_per_eu(1, 1)))
void k_word(
        const __hip_bfloat16* __restrict__ gates,
        const float* __restrict__ whh_f, const float* __restrict__ whh_b,
        __hip_bfloat16* __restrict__ wh) {
    int b = blockIdx.x >> 1, dir = blockIdx.x & 1;
    int tid = threadIdx.x;
    int wv   = tid >> 6;            // wave 0..3
    int lane = tid & 63;
    int q    = lane >> 5;           // k-half: 0 -> even float4 chunks, 1 -> odd
    int u    = wv*32 + (lane & 31); // unit 0..127
    bool act = (u < 100);
    const float* whh = dir ? whh_b : whh_f;
    __shared__ __align__(16) float hs[2][112];   // double-buffered h, padded
    for (int i = tid; i < 224; i += 256) ((float*)hs)[i] = 0.f;
    // weights: W[gate][i] = Whh[gate*100+u][4*(2i+q) .. +3], zero beyond k=100
    float4 W[4][13];
#pragma unroll
    for (int gi = 0; gi < 4; ++gi)
#pragma unroll
        for (int i = 0; i < 13; ++i) {
            int ch = 2*i + q;
            float4 v;
            if (act && ch < 25)
                v = *(const float4*)&whh[(size_t)(gi*100 + u)*100 + ch*4];
            else
                v = make_float4(0.f, 0.f, 0.f, 0.f);
            W[gi][i] = v;
        }
    float cst = 0.f;
    const unsigned short* gp = (const unsigned short*)gates
                             + (size_t)(dir*TOK + b*256)*400;   // [t][gate*100+u]
    __syncthreads();
    int t0 = dir ? 255 : 0;
    unsigned short G0 = 0, G1 = 0, G2 = 0, G3 = 0;
    if (act) {
        const unsigned short* p = gp + (size_t)t0*400 + u;
        G0 = p[0]; G1 = p[100]; G2 = p[200]; G3 = p[300];
    }
    for (int tt = 0; tt < 256; ++tt) {
        int t = dir ? (255 - tt) : tt;
        float gI = bf2f(G0), gF = bf2f(G1), gG = bf2f(G2), gO = bf2f(G3);
        if (tt < 255 && act) {
            int tn = dir ? (t - 1) : (t + 1);
            const unsigned short* p = gp + (size_t)tn*400 + u;
            G0 = p[0]; G1 = p[100]; G2 = p[200]; G3 = p[300];
        }
        const float4* hp = (const float4*)hs[tt & 1];
        float a0 = 0.f, a1 = 0.f, a2 = 0.f, a3 = 0.f;
#pragma unroll
        for (int i = 0; i < 13; ++i) {
            float4 h4 = hp[2*i + q];    // same-addr broadcast per half (free 2-way)
            a0 += W[0][i].x*h4.x + W[0][i].y*h4.y + W[0][i].z*h4.z + W[0][i].w*h4.w;
            a1 += W[1][i].x*h4.x + W[1][i].y*h4.y + W[1][i].z*h4.z + W[1][i].w*h4.w;
            a2 += W[2][i].x*h4.x + W[2][i].y*h4.y + W[2][i].z*h4.z + W[2][i].w*h4.w;
            a3 += W[3][i].x*h4.x + W[3][i].y*h4.y + W[3][i].z*h4.z + W[3][i].w*h4.w;
        }
        a0 += __shfl_xor(a0, 32, 64);
        a1 += __shfl_xor(a1, 32, 64);
        a2 += __shfl_xor(a2, 32, 64);
        a3 += __shfl_xor(a3, 32, 64);
        gI += a0; gF += a1; gG += a2; gO += a3;
        cst = sigf(gF)*cst + sigf(gI)*tanhfast(gG);
        float h = sigf(gO)*tanhfast(cst);
        if (act && q == 0) {
            hs[(tt + 1) & 1][u] = h;
            wh[(size_t)(b*256 + t)*200 + dir*100 + u] = __float2bfloat16(h);
        }
        __syncthreads();
    }
}

// ---- K5: feats = (tanh(wh@W1^T+b1)@W2^T+b2)*mask ; 32 tokens per block
__global__ __launch_bounds__(256) void k_feats(
        const __hip_bfloat16* __restrict__ wh,
        const float* __restrict__ W1, const float* __restrict__ b1,
        const float* __restrict__ W2, const float* __restrict__ b2,
        const int* __restrict__ word_num, float* __restrict__ feats) {
    __shared__ float As[8][32];
    __shared__ float Ws[8][100];
    __shared__ float mids[32][100];
    int tid = threadIdx.x;
    int m0  = blockIdx.x * 32;
    int a_m = tid >> 3, a_k = tid & 7;
    int tn  = tid % 25, tm = tid / 25;   // active: tid < 200
    float acc[4][4] = {};
    for (int k0 = 0; k0 < 200; k0 += 8) {
        float av = __bfloat162float(wh[(size_t)(m0 + a_m)*200 + k0 + a_k]);
        int i1 = tid + 256, i2 = tid + 512, i3 = tid + 768;
        float wv0 = W1[(tid>>3)*200 + k0 + (tid&7)];
        float wv1 = W1[(i1 >>3)*200 + k0 + (i1 &7)];
        float wv2 = W1[(i2 >>3)*200 + k0 + (i2 &7)];
        float wv3 = (i3 < 800) ? W1[(i3>>3)*200 + k0 + (i3&7)] : 0.f;
        __syncthreads();
        As[a_k][a_m] = av;
        Ws[tid&7][tid>>3] = wv0;
        Ws[i1 &7][i1 >>3] = wv1;
        Ws[i2 &7][i2 >>3] = wv2;
        if (i3 < 800) Ws[i3&7][i3>>3] = wv3;
        __syncthreads();
        if (tid < 200) {
#pragma unroll
            for (int kk = 0; kk < 8; ++kk) {
                float4 a4 = *(const float4*)&As[kk][tm*4];
                float4 w4 = *(const float4*)&Ws[kk][tn*4];
                float am[4] = {a4.x, a4.y, a4.z, a4.w};
                float wn[4] = {w4.x, w4.y, w4.z, w4.w};
#pragma unroll
                for (int p = 0; p < 4; ++p)
#pragma unroll
                    for (int q = 0; q < 4; ++q) acc[p][q] += am[p]*wn[q];
            }
        }
    }
    if (tid < 200) {
#pragma unroll
        for (int p = 0; p < 4; ++p)
#pragma unroll
            for (int q = 0; q < 4; ++q)
                mids[tm*4+p][tn*4+q] = tanhfast(acc[p][q] + b1[tn*4+q]);
    }
    __syncthreads();
    for (int idx = tid; idx < 288; idx += 256) {
        int tok = idx / 9, lab = idx - tok*9;
        int m = m0 + tok, bb = m >> 8, s = m & 255;
        float v = b2[lab];
        const float4* mp = (const float4*)mids[tok];
        const float4* wp = (const float4*)(W2 + lab*100);
#pragma unroll
        for (int k = 0; k < 25; ++k) {
            float4 mv = mp[k], wv = wp[k];
            v += mv.x*wv.x + mv.y*wv.y + mv.z*wv.z + mv.w*wv.w;
        }
        feats[(size_t)m*12 + lab] = (s < word_num[bb]) ? v : 0.f;
    }
}

// ---- K6: CRF numerator + log-forward recursion. One wave per batch row.
__global__ __launch_bounds__(64) void k_crf(
        const float* __restrict__ feats, const float* __restrict__ T,
        const int* __restrict__ word_num, const int* __restrict__ label_ids,
        float* __restrict__ perb) {
    int b = blockIdx.x, lane = threadIdx.x;
    int n = word_num[b];
    const int*   lab = label_ids + b*256;
    const float* fb  = feats + (size_t)b*256*12;
    float nm = 0.f;
    for (int t = lane; t < n; t += 64) {
        int lt = lab[t];
        int lp = (t == 0) ? 9 : lab[t-1];
        nm += fb[t*12 + lt] + T[lp*11 + lt];
    }
#pragma unroll
    for (int o = 32; o > 0; o >>= 1) nm += __shfl_down(nm, o, 64);
    nm = __shfl(nm, 0, 64);
    nm += T[lab[n-1]*11 + 10];
    int j = lane;
    float Tc[11];
#pragma unroll
    for (int i = 0; i < 11; ++i) Tc[i] = T[i*11 + (j < 11 ? j : 0)];
    float alpha = (j == 9) ? 0.f : -1000.f;
    for (int t = 0; t < n; ++t) {
        float obs = (j < 9) ? fb[t*12 + j] : -1000.f;
        float v[11], mx = -1e30f;
#pragma unroll
        for (int i = 0; i < 11; ++i) { v[i] = __shfl(alpha, i, 64) + Tc[i]; mx = fmaxf(mx, v[i]); }
        float ssum = 0.f;
#pragma unroll
        for (int i = 0; i < 11; ++i) ssum += __expf(v[i] - mx);
        alpha = obs + mx + __logf(ssum);
    }
    float vv[11], mx = -1e30f, ssum = 0.f;
#pragma unroll
    for (int i = 0; i < 11; ++i) { vv[i] = __shfl(alpha, i, 64) + Tc[i]; mx = fmaxf(mx, vv[i]); }
#pragma unroll
    for (int i = 0; i < 11; ++i) ssum += __expf(vv[i] - mx);
    float denom = __shfl(mx + __logf(ssum), 10, 64);
    if (lane == 0) perb[b] = denom - nm;
}

// ---- K7: mean over batch
__global__ void k_reduce(const float* __restrict__ perb, float* __restrict__ out) {
    int t = threadIdx.x;
    float v = perb[t];
#pragma unroll
    for (int o = 32; o > 0; o >>= 1) v += __shfl_down(v, o, 64);
    __shared__ float sm[2];
    if ((t & 63) == 0) sm[t >> 6] = v;
    __syncthreads();
    if (t == 0) out[0] = (sm[0] + sm[1]) * (1.0f/128.0f);
}

extern "C" void kernel_launch(void* const* d_in, const int* in_sizes, int n_in,
                              void* d_out, int out_size, void* d_ws, size_t ws_size,
                              hipStream_t stream) {
    const float* word_emb = (const float*)d_in[0];
    const float* char_emb = (const float*)d_in[1];
    const float* cWih_f   = (const float*)d_in[2];
    const float* cWhh_f   = (const float*)d_in[3];
    const float* cb_f     = (const float*)d_in[4];
    const float* cWih_b   = (const float*)d_in[5];
    const float* cWhh_b   = (const float*)d_in[6];
    const float* cb_b     = (const float*)d_in[7];
    const float* wWih_f   = (const float*)d_in[8];
    const float* wWhh_f   = (const float*)d_in[9];
    const float* wb_f     = (const float*)d_in[10];
    const float* wWih_b   = (const float*)d_in[11];
    const float* wWhh_b   = (const float*)d_in[12];
    const float* wb_b     = (const float*)d_in[13];
    const float* W1       = (const float*)d_in[14];
    const float* b1       = (const float*)d_in[15];
    const float* W2       = (const float*)d_in[16];
    const float* b2       = (const float*)d_in[17];
    const float* T        = (const float*)d_in[18];
    const int* word_num   = (const int*)d_in[19];
    const int* word_ids   = (const int*)d_in[20];
    const int* char_ids   = (const int*)d_in[21];
    const int* label_ids  = (const int*)d_in[22];

    char* ws = (char*)d_ws;
    float* gin            = (float*)(ws);                       //    80,000 B
    float* Wc             = (float*)(ws + 80000);               //   486,400 B
    float* bc             = (float*)(ws + 566400);              //     3,200 B
    float* wfbuf          = (float*)(ws + 569600);              // 19,922,944 B [32768][152]
    __hip_bfloat16* gates = (__hip_bfloat16*)(ws + 20492544);   // 52,428,800 B [2][32768][400]
    __hip_bfloat16* wh    = (__hip_bfloat16*)(ws + 72921344);   // 13,107,200 B [32768][200]
    float* feats          = (float*)(ws + 86028544);            //  1,572,864 B [32768][12]
    float* perb           = (float*)(ws + 87601408);            //       512 B

    k_gin   <<<4, 64, 0, stream>>>(char_emb, cWih_f, cb_f, cWih_b, cb_b, gin);
    k_wcomb <<<(800*152 + 255)/256, 256, 0, stream>>>(wWih_f, wb_f, wWih_b, wb_b, Wc, bc);
    k_gather<<<(TOK*152)/256, 256, 0, stream>>>(word_emb, word_ids, wfbuf);
    k_char  <<<8192, 256, 0, stream>>>(gin, cWhh_f, cWhh_b, char_ids, word_num, wfbuf);
    k_gemm_in<<<512*13, 256, 0, stream>>>(wfbuf, Wc, bc, gates);
    k_word  <<<256, 256, 0, stream>>>(gates, wWhh_f, wWhh_b, wh);
    k_feats <<<1024, 256, 0, stream>>>(wh, W1, b1, W2, b2, word_num, feats);
    k_crf   <<<128, 64, 0, stream>>>(feats, T, word_num, label_ids, perb);
    k_reduce<<<1, 128, 0, stream>>>(perb, (float*)d_out);
}